// Round 1
// baseline (101.310 us; speedup 1.0000x reference)
//
#include <hip/hip_runtime.h>

// AudioWaveAugment: out = filter(gain(x) + noise_term), per-row params.
//   g  = do_gain<0.7 ? gains : 1
//   cn = (do_noise<0.5) * max(g*std(x), 1e-4) * noise_scales   (std over row, ddof=1)
//   x2 = g*x + cn*noise
//   low = moving-average(x2, k=2*half+1, zero-padded)
//   out = do_filter<0.35 ? (low_coin<0.5 ? low : x2-low) : x2

#define NBPR 8           // reduction blocks per row
#define TILE 4096        // samples per main-kernel block
#define HMAX 16          // max half-window (PAD in reference)
#define EXT (TILE + 2*HMAX)
#define PADIDX(i) ((i) + ((i) >> 4))   // +1 pad per 16 floats -> lane-stride 17 (conflict-free)

// ---------------- K1: per-row partial sum / sumsq (only rows that need std) --------
__global__ __launch_bounds__(256) void k_rowsum(
    const float* __restrict__ x, const float* __restrict__ do_noise,
    float* __restrict__ partials, int rowlen)
{
    int row = blockIdx.x / NBPR;
    int blk = blockIdx.x % NBPR;
    if (do_noise[row] >= 0.5f) return;   // cn==0 for this row; std never used

    long long rowoff = (long long)row * rowlen;
    int chunk = (rowlen + NBPR - 1) / NBPR;
    long long start = (long long)blk * chunk;
    long long end = start + chunk; if (end > rowlen) end = rowlen;
    float s = 0.f, s2 = 0.f;
    if (start < end) {
        const float* xr = x + rowoff;
        long long a0 = (start + 3) & ~3LL;
        long long a1 = end & ~3LL;
        bool al = ((rowoff & 3) == 0);
        if (al && a1 > a0) {
            for (long long i = start + threadIdx.x; i < a0; i += 256) { float v = xr[i]; s += v; s2 += v*v; }
            const float4* x4 = (const float4*)xr;
            for (long long i = a0/4 + threadIdx.x; i < a1/4; i += 256) {
                float4 v = x4[i];
                s  += v.x + v.y + v.z + v.w;
                s2 += v.x*v.x + v.y*v.y + v.z*v.z + v.w*v.w;
            }
            for (long long i = a1 + threadIdx.x; i < end; i += 256) { float v = xr[i]; s += v; s2 += v*v; }
        } else {
            for (long long i = start + threadIdx.x; i < end; i += 256) { float v = xr[i]; s += v; s2 += v*v; }
        }
    }
    for (int o = 32; o; o >>= 1) { s += __shfl_down(s, o); s2 += __shfl_down(s2, o); }
    __shared__ float ls[4], ls2[4];
    int wid = threadIdx.x >> 6, lane = threadIdx.x & 63;
    if (lane == 0) { ls[wid] = s; ls2[wid] = s2; }
    __syncthreads();
    if (threadIdx.x == 0) {
        float a = 0.f, b = 0.f;
        for (int w = 0; w < 4; ++w) { a += ls[w]; b += ls2[w]; }
        partials[(row*NBPR + blk)*2 + 0] = a;
        partials[(row*NBPR + blk)*2 + 1] = b;
    }
}

// ---------------- K2: per-row parameters -------------------------------------------
__global__ void k_params(
    const float* __restrict__ partials,
    const float* __restrict__ gains, const float* __restrict__ nscales,
    const float* __restrict__ do_gain, const float* __restrict__ do_noise,
    const float* __restrict__ do_filter, const float* __restrict__ low_coin,
    const int* __restrict__ halves,
    float* __restrict__ gp, float* __restrict__ cnp, float* __restrict__ ivkp,
    int* __restrict__ halfp, int* __restrict__ modep,
    int B, long long N)
{
    int b = blockIdx.x * blockDim.x + threadIdx.x;
    if (b >= B) return;
    float g = (do_gain[b] < 0.7f) ? gains[b] : 1.0f;
    float cn = 0.f;
    if (do_noise[b] < 0.5f) {
        double s = 0.0, s2 = 0.0;
        for (int i = 0; i < NBPR; ++i) {
            s  += (double)partials[(b*NBPR + i)*2 + 0];
            s2 += (double)partials[(b*NBPR + i)*2 + 1];
        }
        double var = (s2 - s*s/(double)N) / (double)(N - 1);
        if (var < 0.0) var = 0.0;
        float stdx = (float)sqrt(var);
        float std1 = fmaxf(g * stdx, 1e-4f);   // std(g*x)=g*std(x), clip at 1e-4
        cn = std1 * nscales[b];
    }
    int half = halves[b];
    int mode = (do_filter[b] < 0.35f) ? ((low_coin[b] < 0.5f) ? 1 : 2) : 0;
    gp[b] = g; cnp[b] = cn; ivkp[b] = 1.0f / (float)(2*half + 1);
    halfp[b] = half; modep[b] = mode;
}

// ---------------- K3: fused gain+noise+filter --------------------------------------
__global__ __launch_bounds__(256) void k_main(
    const float* __restrict__ x, const float* __restrict__ noise,
    const float* __restrict__ gp, const float* __restrict__ cnp,
    const float* __restrict__ ivkp, const int* __restrict__ halfp,
    const int* __restrict__ modep, float* __restrict__ out, int rowlen)
{
    __shared__ float xs[PADIDX(EXT) + 2];
    int row = blockIdx.y;
    int tid = threadIdx.x;
    long long rowoff = (long long)row * rowlen;
    int s = blockIdx.x * TILE;
    int mode = modep[row];
    float g = gp[row], cn = cnp[row];
    bool use_noise = (cn != 0.f);
    int tlim = rowlen - s; if (tlim > TILE) tlim = TILE;

    if (mode == 0) {
        // out = x2, pure streaming
        const float* xr = x + rowoff + s;
        const float* nr = noise + rowoff + s;
        float* orow = out + rowoff + s;
        bool al = (((rowoff + s) & 3) == 0);
        int n4 = al ? (tlim >> 2) : 0;
        for (int i = tid; i < n4; i += 256) {
            float4 xv = ((const float4*)xr)[i];
            float4 r;
            if (use_noise) {
                float4 nv = ((const float4*)nr)[i];
                r.x = g*xv.x + cn*nv.x; r.y = g*xv.y + cn*nv.y;
                r.z = g*xv.z + cn*nv.z; r.w = g*xv.w + cn*nv.w;
            } else {
                r.x = g*xv.x; r.y = g*xv.y; r.z = g*xv.z; r.w = g*xv.w;
            }
            ((float4*)orow)[i] = r;
        }
        for (int i = (n4 << 2) + tid; i < tlim; i += 256) {
            float v = g * xr[i];
            if (use_noise) v += cn * nr[i];
            orow[i] = v;
        }
        return;
    }

    int half = halfp[row];
    float ivk = ivkp[row];

    // stage x2 for [s-HMAX, s+TILE+HMAX) into padded LDS, zero outside [0,rowlen)
    long long base = (long long)s - HMAX;
    bool al = (((rowoff + base) & 3) == 0);
    for (int c4 = tid; c4 < EXT/4; c4 += 256) {
        long long gi = base + 4*(long long)c4;
        float v0, v1, v2, v3;
        if (al && gi >= 0 && gi + 3 < rowlen) {
            float4 xv = *(const float4*)(x + rowoff + gi);
            if (use_noise) {
                float4 nv = *(const float4*)(noise + rowoff + gi);
                v0 = g*xv.x + cn*nv.x; v1 = g*xv.y + cn*nv.y;
                v2 = g*xv.z + cn*nv.z; v3 = g*xv.w + cn*nv.w;
            } else {
                v0 = g*xv.x; v1 = g*xv.y; v2 = g*xv.z; v3 = g*xv.w;
            }
        } else {
            float vv[4];
            #pragma unroll
            for (int j = 0; j < 4; ++j) {
                long long t = gi + j;
                float v = 0.f;
                if (t >= 0 && t < rowlen) {
                    v = g * x[rowoff + t];
                    if (use_noise) v += cn * noise[rowoff + t];
                }
                vv[j] = v;
            }
            v0 = vv[0]; v1 = vv[1]; v2 = vv[2]; v3 = vv[3];
        }
        int e = 4*c4;
        int p = PADIDX(e);            // e%4==0 -> e..e+3 share a 16-group, pad offset constant
        xs[p] = v0; xs[p+1] = v1; xs[p+2] = v2; xs[p+3] = v3;
    }
    __syncthreads();

    // each thread: 16 contiguous outputs via sliding-window sum (2 LDS reads/elem)
    int c = tid << 4;
    float w = 0.f;
    {
        int lo = c + HMAX - half, hi = c + HMAX + half;
        for (int j = lo; j <= hi; ++j) w += xs[PADIDX(j)];
    }
    float* orow = out + rowoff + s;
    bool al4 = (((rowoff + s) & 3) == 0);
    for (int q = 0; q < 4; ++q) {
        float r[4];
        #pragma unroll
        for (int j = 0; j < 4; ++j) {
            int l = c + q*4 + j;
            float x2v = xs[PADIDX(l + HMAX)];
            float low = w * ivk;
            r[j] = (mode == 1) ? low : (x2v - low);
            if ((q*4 + j) < 15) {   // slide; skip after the last element
                w += xs[PADIDX(l + 1 + HMAX + half)] - xs[PADIDX(l + HMAX - half)];
            }
        }
        int o0 = c + q*4;
        if (al4 && o0 + 3 < tlim) {
            float4 rv; rv.x = r[0]; rv.y = r[1]; rv.z = r[2]; rv.w = r[3];
            *(float4*)(orow + o0) = rv;
        } else {
            for (int j = 0; j < 4; ++j) if (o0 + j < tlim) orow[o0 + j] = r[j];
        }
    }
}

extern "C" void kernel_launch(void* const* d_in, const int* in_sizes, int n_in,
                              void* d_out, int out_size, void* d_ws, size_t ws_size,
                              hipStream_t stream)
{
    const float* x         = (const float*)d_in[0];
    const float* gains     = (const float*)d_in[1];
    const float* nscales   = (const float*)d_in[2];
    const float* noise     = (const float*)d_in[3];
    const float* do_gain   = (const float*)d_in[4];
    const float* do_noise  = (const float*)d_in[5];
    const float* do_filter = (const float*)d_in[6];
    const float* low_coin  = (const float*)d_in[7];
    const int*   halves    = (const int*)d_in[8];

    int B = in_sizes[1];
    long long N = (long long)in_sizes[0] / B;   // C*T per row (C==1)
    int rowlen = (int)N;

    float* partials = (float*)d_ws;                       // B*NBPR*2 floats
    float* gp   = partials + (size_t)B * NBPR * 2;
    float* cnp  = gp + B;
    float* ivkp = cnp + B;
    int*   halfp = (int*)(ivkp + B);
    int*   modep = halfp + B;

    k_rowsum<<<dim3(B * NBPR), dim3(256), 0, stream>>>(x, do_noise, partials, rowlen);
    k_params<<<dim3((B + 127)/128), dim3(128), 0, stream>>>(
        partials, gains, nscales, do_gain, do_noise, do_filter, low_coin, halves,
        gp, cnp, ivkp, halfp, modep, B, N);
    int tiles = (rowlen + TILE - 1) / TILE;
    k_main<<<dim3(tiles, B), dim3(256), 0, stream>>>(
        x, noise, gp, cnp, ivkp, halfp, modep, (float*)d_out, rowlen);
}